// Round 4
// baseline (222.931 us; speedup 1.0000x reference)
//
#include <hip/hip_runtime.h>
#include <math.h>

#define EPSF 1e-12f

typedef short bf16x8 __attribute__((ext_vector_type(8)));
typedef float f32x4 __attribute__((ext_vector_type(4)));

__device__ __forceinline__ void gload_lds16(const void* g, void* l) {
  __builtin_amdgcn_global_load_lds(
      (const __attribute__((address_space(1))) unsigned int*)g,
      (__attribute__((address_space(3))) unsigned int*)l, 16, 0, 0);
}

__device__ __forceinline__ unsigned short bf16_rne(float f) {
  unsigned int u = __float_as_uint(f);
  u += 0x7fffu + ((u >> 16) & 1u);
  return (unsigned short)(u >> 16);
}

__device__ __forceinline__ float bf16_to_f32(unsigned short h) {
  return __uint_as_float((unsigned int)h << 16);
}

// ---------------- block reduce (256 threads, wave64) ----------------
__device__ __forceinline__ float block_reduce_sum_256(float v) {
#pragma unroll
  for (int o = 32; o > 0; o >>= 1) v += __shfl_down(v, o, 64);
  __shared__ float ws4[4];
  const int lane = threadIdx.x & 63;
  const int w = threadIdx.x >> 6;
  if (lane == 0) ws4[w] = v;
  __syncthreads();
  if (threadIdx.x == 0) ws4[0] = ws4[0] + ws4[1] + ws4[2] + ws4[3];
  __syncthreads();
  return ws4[0];
}

// ---------------- stage 1: src readout -> bf16 [4096,512] + row sq-norm ----------------
__global__ __launch_bounds__(256) void k_src_readout(const float* __restrict__ m,
                                                     const int* __restrict__ src_mask,
                                                     unsigned short* __restrict__ srcRb,
                                                     float* __restrict__ ssq) {
  const int b = blockIdx.x;
  __shared__ int msk[32];
  __shared__ float s_inv;
  const int tid = threadIdx.x;
  if (tid < 32) msk[tid] = src_mask[b * 32 + tid];
  __syncthreads();
  if (tid == 0) {
    float c = 0.f;
    for (int s = 0; s < 32; ++s) c += (float)msk[s];
    s_inv = 1.0f / fmaxf(c, EPSF);
  }
  __syncthreads();
  const float inv = s_inv;
  const float* mb = m + (size_t)b * (32 * 512) + 2 * tid;
  float ax = 0.f, ay = 0.f;
  for (int s = 0; s < 32; ++s) {
    if (msk[s] != 0) {
      float2 v = *(const float2*)(mb + s * 512);
      ax += v.x;
      ay += v.y;
    }
  }
  ushort2 o;
  o.x = bf16_rne(ax * inv);
  o.y = bf16_rne(ay * inv);
  *(ushort2*)(srcRb + (size_t)b * 512 + 2 * tid) = o;
  float fx = bf16_to_f32(o.x), fy = bf16_to_f32(o.y);
  float s = fx * fx + fy * fy;
  s = block_reduce_sum_256(s);
  if (tid == 0) ssq[b] = s;
}

// ---------------- stage 2: tgt readout -> bf16 [8192,512] ----------------
#define TR_LDW 257
__global__ __launch_bounds__(256) void k_tgt_readout(const float* __restrict__ om,
                                                     const int* __restrict__ tgt_mask,
                                                     unsigned short* __restrict__ tgtRb) {
  const int b = blockIdx.x, tt = blockIdx.y, dt = blockIdx.z;
  const int t0 = tt * 64, d0 = dt * 128;
  __shared__ float wm[64 * TR_LDW];
  __shared__ float cpart[256];
  __shared__ float s_inv[64];
  const int tid = threadIdx.x;
  const int* mbase = tgt_mask + ((size_t)(b * 256 + t0)) * 256;
  for (int i = 0; i < 64; ++i) {
    int idx = tid + 256 * i;
    wm[(idx >> 8) * TR_LDW + (idx & 255)] = (float)mbase[idx];
  }
  __syncthreads();
  {
    const int r = tid >> 2, q = tid & 3;
    float c = 0.f;
    for (int u = 0; u < 64; ++u) c += wm[r * TR_LDW + q * 64 + u];
    cpart[tid] = c;
  }
  __syncthreads();
  if (tid < 64) {
    float c = cpart[4 * tid] + cpart[4 * tid + 1] + cpart[4 * tid + 2] + cpart[4 * tid + 3];
    s_inv[tid] = 1.0f / fmaxf(c, EPSF);
  }
  __syncthreads();
  const int tx = tid & 31, ty = tid >> 5;
  float4 acc[8];
#pragma unroll
  for (int j = 0; j < 8; ++j) acc[j] = make_float4(0.f, 0.f, 0.f, 0.f);
  const float* ob = om + (size_t)b * 256 * 512 + d0 + tx * 4;
  for (int u = 0; u < 256; ++u) {
    float4 o = *(const float4*)(ob + (size_t)u * 512);
#pragma unroll
    for (int j = 0; j < 8; ++j) {
      float w = wm[(ty * 8 + j) * TR_LDW + u];
      acc[j].x += o.x * w;
      acc[j].y += o.y * w;
      acc[j].z += o.z * w;
      acc[j].w += o.w * w;
    }
  }
#pragma unroll
  for (int j = 0; j < 8; ++j) {
    const int t = ty * 8 + j;
    const float inv = s_inv[t];
    ushort4 r;
    r.x = bf16_rne(acc[j].x * inv);
    r.y = bf16_rne(acc[j].y * inv);
    r.z = bf16_rne(acc[j].z * inv);
    r.w = bf16_rne(acc[j].w * inv);
    *(ushort4*)(tgtRb + ((size_t)(b * 256 + t0 + t)) * 512 + d0 + tx * 4) = r;
  }
}

// ---------------- stage 2b: row squared norms from bf16 ----------------
__global__ __launch_bounds__(256) void k_rowsq_bf16(const unsigned short* __restrict__ X,
                                                    float* __restrict__ sq) {
  const int r = blockIdx.x;
  const int tid = threadIdx.x;
  ushort2 v = *(const ushort2*)(X + (size_t)r * 512 + 2 * tid);
  float fx = bf16_to_f32(v.x), fy = bf16_to_f32(v.y);
  float s = fx * fx + fy * fy;
  s = block_reduce_sum_256(s);
  if (tid == 0) sq[r] = s;
}

// ---------------- stage 3: cross GEMM (bf16 MFMA) + dist + exp ----------------
// C[M=8192, N=4096], K=512. 128x128 tile, BK=64 (2 sub-tiles of 32), 4 waves,
// wave = 64x64 (4x4 x 16x16x32). LDS fragment order per 32-k sub-tile:
// 16-row block b, lane l -> row (l&15), k (l>>4)*8..+7 ; 16B/lane.
// WRITE_BF16: 1 -> write unnormalized sim as bf16 to simU; 0 -> f32 to out buffer.
template <int WRITE_BF16>
__global__ __launch_bounds__(256) void k_cross_mfma(
    const unsigned short* __restrict__ A, const unsigned short* __restrict__ B,
    const float* __restrict__ tsq, const float* __restrict__ ssq,
    unsigned short* __restrict__ simU, float* __restrict__ outF) {
  __shared__ unsigned short As[2 * 128 * 32];
  __shared__ unsigned short Bs[2 * 128 * 32];
  const int tid = threadIdx.x;
  const int lane = tid & 63, w = tid >> 6;
  const int wm = w >> 1, wn = w & 1;
  // XCD-aware bijective swizzle: 2048 blocks = 8 XCDs x 256
  const int bid = blockIdx.x;
  const int swz = (bid & 7) * 256 + (bid >> 3);
  const int bn = swz & 31, bm = swz >> 5;
  const int row0 = bm * 128, col0 = bn * 128;

  f32x4 acc[4][4];
#pragma unroll
  for (int i = 0; i < 4; ++i)
#pragma unroll
    for (int j = 0; j < 4; ++j) acc[i][j] = (f32x4){0.f, 0.f, 0.f, 0.f};

  const int lr = lane & 15, lkw = (lane >> 4) * 8;
  const size_t aoff0 = (size_t)(row0 + (w * 2) * 16 + lr) * 512 + lkw;
  const size_t aoff1 = aoff0 + 16 * 512;
  const size_t boff0 = (size_t)(col0 + (w * 2) * 16 + lr) * 512 + lkw;
  const size_t boff1 = boff0 + 16 * 512;
  unsigned short* ldsA00 = As + (w * 2) * 512;
  unsigned short* ldsA01 = As + (w * 2 + 1) * 512;
  unsigned short* ldsA10 = As + 4096 + (w * 2) * 512;
  unsigned short* ldsA11 = As + 4096 + (w * 2 + 1) * 512;
  unsigned short* ldsB00 = Bs + (w * 2) * 512;
  unsigned short* ldsB01 = Bs + (w * 2 + 1) * 512;
  unsigned short* ldsB10 = Bs + 4096 + (w * 2) * 512;
  unsigned short* ldsB11 = Bs + 4096 + (w * 2 + 1) * 512;

  for (int kt = 0; kt < 8; ++kt) {
    const int kb = kt * 64;
    __syncthreads();  // previous iteration's ds_reads done before overwrite
    gload_lds16(A + aoff0 + kb, ldsA00);
    gload_lds16(A + aoff1 + kb, ldsA01);
    gload_lds16(A + aoff0 + kb + 32, ldsA10);
    gload_lds16(A + aoff1 + kb + 32, ldsA11);
    gload_lds16(B + boff0 + kb, ldsB00);
    gload_lds16(B + boff1 + kb, ldsB01);
    gload_lds16(B + boff0 + kb + 32, ldsB10);
    gload_lds16(B + boff1 + kb + 32, ldsB11);
    __syncthreads();  // staging complete (compiler drains vmcnt before barrier)
#pragma unroll
    for (int kk = 0; kk < 2; ++kk) {
      const int sb = kk * 4096;
      bf16x8 af[4], bfr[4];
#pragma unroll
      for (int i = 0; i < 4; ++i) {
        af[i] = *(const bf16x8*)(As + sb + ((wm * 4 + i) * 64 + lane) * 8);
        bfr[i] = *(const bf16x8*)(Bs + sb + ((wn * 4 + i) * 64 + lane) * 8);
      }
#pragma unroll
      for (int i = 0; i < 4; ++i)
#pragma unroll
        for (int j = 0; j < 4; ++j)
          acc[i][j] = __builtin_amdgcn_mfma_f32_16x16x32_bf16(af[i], bfr[j], acc[i][j], 0, 0, 0);
    }
  }

  // epilogue: d2 = t2 + s2 - 2c ; sim = exp(-sqrt(max(d2,eps)))
  // C/D layout: col = lane&15, row = (lane>>4)*4 + reg  [m89-verified]
  const int cbase = col0 + wn * 64 + (lane & 15);
  const int rbase = row0 + wm * 64 + (lane >> 4) * 4;
  float ss[4];
#pragma unroll
  for (int j = 0; j < 4; ++j) ss[j] = ssq[cbase + j * 16];
#pragma unroll
  for (int i = 0; i < 4; ++i) {
#pragma unroll
    for (int r = 0; r < 4; ++r) {
      const int row = rbase + i * 16 + r;
      const float t2 = tsq[row];
#pragma unroll
      for (int j = 0; j < 4; ++j) {
        float d2 = t2 + ss[j] - 2.0f * acc[i][j][r];
        float sim = expf(-sqrtf(fmaxf(d2, EPSF)));
        if (WRITE_BF16) {
          simU[(size_t)row * 4096 + cbase + j * 16] = bf16_rne(sim);
        } else {
          outF[(size_t)row * 4096 + cbase + j * 16] = sim;
        }
      }
    }
  }
}

// ---------------- stage 4a: row L1 normalize from bf16 unnorm -> f32 out ----------------
__global__ __launch_bounds__(256) void k_norm_bf16(const unsigned short* __restrict__ simU,
                                                   float* __restrict__ out) {
  const size_t base = (size_t)blockIdx.x * 4096;
  const int tid = threadIdx.x;
  float f[16];
  float s = 0.f;
#pragma unroll
  for (int i = 0; i < 4; ++i) {
    ushort4 v = *(const ushort4*)(simU + base + (size_t)(tid * 4 + i * 1024));
    f[4 * i + 0] = bf16_to_f32(v.x);
    f[4 * i + 1] = bf16_to_f32(v.y);
    f[4 * i + 2] = bf16_to_f32(v.z);
    f[4 * i + 3] = bf16_to_f32(v.w);
    s += f[4 * i + 0] + f[4 * i + 1] + f[4 * i + 2] + f[4 * i + 3];
  }
  s = block_reduce_sum_256(s);
  const float inv = 1.0f / fmaxf(s, EPSF);
#pragma unroll
  for (int i = 0; i < 4; ++i) {
    float4 r;
    r.x = f[4 * i + 0] * inv;
    r.y = f[4 * i + 1] * inv;
    r.z = f[4 * i + 2] * inv;
    r.w = f[4 * i + 3] * inv;
    *(float4*)(out + base + (size_t)(tid * 4 + i * 1024)) = r;
  }
}

// ---------------- stage 4b: fallback in-place f32 normalize ----------------
__global__ __launch_bounds__(256) void k_norm_f32(float* __restrict__ out) {
  const size_t base = (size_t)blockIdx.x * 4096;
  const int tid = threadIdx.x;
  float4 v[4];
  float s = 0.f;
#pragma unroll
  for (int i = 0; i < 4; ++i) {
    v[i] = *(const float4*)(out + base + (size_t)(tid * 4 + i * 1024));
    s += v[i].x + v[i].y + v[i].z + v[i].w;
  }
  s = block_reduce_sum_256(s);
  const float inv = 1.0f / fmaxf(s, EPSF);
#pragma unroll
  for (int i = 0; i < 4; ++i) {
    float4 r;
    r.x = v[i].x * inv;
    r.y = v[i].y * inv;
    r.z = v[i].z * inv;
    r.w = v[i].w * inv;
    *(float4*)(out + base + (size_t)(tid * 4 + i * 1024)) = r;
  }
}

extern "C" void kernel_launch(void* const* d_in, const int* in_sizes, int n_in,
                              void* d_out, int out_size, void* d_ws, size_t ws_size,
                              hipStream_t stream) {
  const float* m = (const float*)d_in[0];        // [4096,32,512]
  const float* om = (const float*)d_in[1];       // [32,256,512]
  const int* src_mask = (const int*)d_in[2];     // [4096,1,32]
  const int* tgt_mask = (const int*)d_in[3];     // [32,256,256]
  float* out = (float*)d_out;                    // [32,256,4096]

  float* ws = (float*)d_ws;
  float* ssq = ws;                                         // 4096 f32
  float* tsq = ssq + 4096;                                 // 8192 f32
  unsigned short* srcRb = (unsigned short*)(tsq + 8192);   // 4096*512 bf16
  unsigned short* tgtRb = srcRb + 4096 * 512;              // 8192*512 bf16
  unsigned short* simU = tgtRb + (size_t)8192 * 512;       // 8192*4096 bf16

  const size_t need_bf16 = (size_t)(4096 + 8192) * 4 +
                           ((size_t)4096 * 512 + (size_t)8192 * 512) * 2 +
                           (size_t)8192 * 4096 * 2;
  const bool use_bf16_out = ws_size >= need_bf16;

  k_src_readout<<<4096, 256, 0, stream>>>(m, src_mask, srcRb, ssq);
  k_tgt_readout<<<dim3(32, 4, 4), 256, 0, stream>>>(om, tgt_mask, tgtRb);
  k_rowsq_bf16<<<8192, 256, 0, stream>>>(tgtRb, tsq);
  if (use_bf16_out) {
    k_cross_mfma<1><<<2048, 256, 0, stream>>>(tgtRb, srcRb, tsq, ssq, simU, out);
    k_norm_bf16<<<8192, 256, 0, stream>>>(simU, out);
  } else {
    k_cross_mfma<0><<<2048, 256, 0, stream>>>(tgtRb, srcRb, tsq, ssq, simU, out);
    k_norm_f32<<<8192, 256, 0, stream>>>(out);
  }
}

// Round 5
// 213.725 us; speedup vs baseline: 1.0431x; 1.0431x over previous
//
#include <hip/hip_runtime.h>
#include <math.h>

#define EPSF 1e-12f

typedef short bf16x8 __attribute__((ext_vector_type(8)));
typedef float f32x4 __attribute__((ext_vector_type(4)));

__device__ __forceinline__ void gload_lds16(const void* g, void* l) {
  __builtin_amdgcn_global_load_lds(
      (const __attribute__((address_space(1))) unsigned int*)g,
      (__attribute__((address_space(3))) unsigned int*)l, 16, 0, 0);
}

__device__ __forceinline__ unsigned short bf16_rne(float f) {
  unsigned int u = __float_as_uint(f);
  u += 0x7fffu + ((u >> 16) & 1u);
  return (unsigned short)(u >> 16);
}

__device__ __forceinline__ float bf16_to_f32(unsigned short h) {
  return __uint_as_float((unsigned int)h << 16);
}

// ---------------- block reduce (256 threads, wave64) ----------------
__device__ __forceinline__ float block_reduce_sum_256(float v) {
#pragma unroll
  for (int o = 32; o > 0; o >>= 1) v += __shfl_down(v, o, 64);
  __shared__ float ws4[4];
  const int lane = threadIdx.x & 63;
  const int w = threadIdx.x >> 6;
  if (lane == 0) ws4[w] = v;
  __syncthreads();
  if (threadIdx.x == 0) ws4[0] = ws4[0] + ws4[1] + ws4[2] + ws4[3];
  __syncthreads();
  return ws4[0];
}

// ---------------- stage 1: src readout -> bf16 [4096,512] + row sq-norm ----------------
__global__ __launch_bounds__(256) void k_src_readout(const float* __restrict__ m,
                                                     const int* __restrict__ src_mask,
                                                     unsigned short* __restrict__ srcRb,
                                                     float* __restrict__ ssq) {
  const int b = blockIdx.x;
  __shared__ int msk[32];
  __shared__ float s_inv;
  const int tid = threadIdx.x;
  if (tid < 32) msk[tid] = src_mask[b * 32 + tid];
  __syncthreads();
  if (tid == 0) {
    float c = 0.f;
    for (int s = 0; s < 32; ++s) c += (float)msk[s];
    s_inv = 1.0f / fmaxf(c, EPSF);
  }
  __syncthreads();
  const float inv = s_inv;
  const float* mb = m + (size_t)b * (32 * 512) + 2 * tid;
  float ax = 0.f, ay = 0.f;
  for (int s = 0; s < 32; ++s) {
    if (msk[s] != 0) {
      float2 v = *(const float2*)(mb + s * 512);
      ax += v.x;
      ay += v.y;
    }
  }
  ushort2 o;
  o.x = bf16_rne(ax * inv);
  o.y = bf16_rne(ay * inv);
  *(ushort2*)(srcRb + (size_t)b * 512 + 2 * tid) = o;
  float fx = bf16_to_f32(o.x), fy = bf16_to_f32(o.y);
  float s = fx * fx + fy * fy;
  s = block_reduce_sum_256(s);
  if (tid == 0) ssq[b] = s;
}

// ---------------- stage 2: tgt readout -> bf16 [8192,512] ----------------
#define TR_LDW 257
__global__ __launch_bounds__(256) void k_tgt_readout(const float* __restrict__ om,
                                                     const int* __restrict__ tgt_mask,
                                                     unsigned short* __restrict__ tgtRb) {
  const int b = blockIdx.x, tt = blockIdx.y, dt = blockIdx.z;
  const int t0 = tt * 64, d0 = dt * 128;
  __shared__ float wm[64 * TR_LDW];
  __shared__ float cpart[256];
  __shared__ float s_inv[64];
  const int tid = threadIdx.x;
  const int* mbase = tgt_mask + ((size_t)(b * 256 + t0)) * 256;
  for (int i = 0; i < 64; ++i) {
    int idx = tid + 256 * i;
    wm[(idx >> 8) * TR_LDW + (idx & 255)] = (float)mbase[idx];
  }
  __syncthreads();
  {
    const int r = tid >> 2, q = tid & 3;
    float c = 0.f;
    for (int u = 0; u < 64; ++u) c += wm[r * TR_LDW + q * 64 + u];
    cpart[tid] = c;
  }
  __syncthreads();
  if (tid < 64) {
    float c = cpart[4 * tid] + cpart[4 * tid + 1] + cpart[4 * tid + 2] + cpart[4 * tid + 3];
    s_inv[tid] = 1.0f / fmaxf(c, EPSF);
  }
  __syncthreads();
  const int tx = tid & 31, ty = tid >> 5;
  float4 acc[8];
#pragma unroll
  for (int j = 0; j < 8; ++j) acc[j] = make_float4(0.f, 0.f, 0.f, 0.f);
  const float* ob = om + (size_t)b * 256 * 512 + d0 + tx * 4;
  for (int u = 0; u < 256; ++u) {
    float4 o = *(const float4*)(ob + (size_t)u * 512);
#pragma unroll
    for (int j = 0; j < 8; ++j) {
      float w = wm[(ty * 8 + j) * TR_LDW + u];
      acc[j].x += o.x * w;
      acc[j].y += o.y * w;
      acc[j].z += o.z * w;
      acc[j].w += o.w * w;
    }
  }
#pragma unroll
  for (int j = 0; j < 8; ++j) {
    const int t = ty * 8 + j;
    const float inv = s_inv[t];
    ushort4 r;
    r.x = bf16_rne(acc[j].x * inv);
    r.y = bf16_rne(acc[j].y * inv);
    r.z = bf16_rne(acc[j].z * inv);
    r.w = bf16_rne(acc[j].w * inv);
    *(ushort4*)(tgtRb + ((size_t)(b * 256 + t0 + t)) * 512 + d0 + tx * 4) = r;
  }
}

// ---------------- stage 2b: row squared norms from bf16 ----------------
__global__ __launch_bounds__(256) void k_rowsq_bf16(const unsigned short* __restrict__ X,
                                                    float* __restrict__ sq) {
  const int r = blockIdx.x;
  const int tid = threadIdx.x;
  ushort2 v = *(const ushort2*)(X + (size_t)r * 512 + 2 * tid);
  float fx = bf16_to_f32(v.x), fy = bf16_to_f32(v.y);
  float s = fx * fx + fy * fy;
  s = block_reduce_sum_256(s);
  if (tid == 0) sq[r] = s;
}

// ---------------- stage 3: cross GEMM (bf16 MFMA) + dist + exp ----------------
// C[M=8192, N=4096], K=512. 128x128 tile, BK=32, 4 waves, wave = 64x64 (4x4 x 16x16x32).
// LDS fragment order: 16-row block b, lane l -> row (l&15), k (l>>4)*8..+7 ; 16B/lane.
// Exactly the round-2 structure (measured-good); only the output write differs.
// WRITE_BF16: 1 -> write unnormalized sim as bf16 to simU; 0 -> f32 to out buffer.
template <int WRITE_BF16>
__global__ __launch_bounds__(256) void k_cross_mfma(
    const unsigned short* __restrict__ A, const unsigned short* __restrict__ B,
    const float* __restrict__ tsq, const float* __restrict__ ssq,
    unsigned short* __restrict__ simU, float* __restrict__ outF) {
  __shared__ unsigned short As[128 * 32];
  __shared__ unsigned short Bs[128 * 32];
  const int tid = threadIdx.x;
  const int lane = tid & 63, w = tid >> 6;
  const int wm = w >> 1, wn = w & 1;
  const int row0 = blockIdx.y * 128, col0 = blockIdx.x * 128;

  f32x4 acc[4][4];
#pragma unroll
  for (int i = 0; i < 4; ++i)
#pragma unroll
    for (int j = 0; j < 4; ++j) acc[i][j] = (f32x4){0.f, 0.f, 0.f, 0.f};

  const int lr = lane & 15, lkw = (lane >> 4) * 8;
  const size_t aoff0 = (size_t)(row0 + (w * 2) * 16 + lr) * 512 + lkw;
  const size_t aoff1 = aoff0 + 16 * 512;
  const size_t boff0 = (size_t)(col0 + (w * 2) * 16 + lr) * 512 + lkw;
  const size_t boff1 = boff0 + 16 * 512;
  unsigned short* ldsA0 = As + (w * 2) * 512;
  unsigned short* ldsA1 = As + (w * 2 + 1) * 512;
  unsigned short* ldsB0 = Bs + (w * 2) * 512;
  unsigned short* ldsB1 = Bs + (w * 2 + 1) * 512;

  for (int kt = 0; kt < 16; ++kt) {
    const int kb = kt * 32;
    __syncthreads();  // previous iteration's ds_reads done before overwrite
    gload_lds16(A + aoff0 + kb, ldsA0);
    gload_lds16(A + aoff1 + kb, ldsA1);
    gload_lds16(B + boff0 + kb, ldsB0);
    gload_lds16(B + boff1 + kb, ldsB1);
    __syncthreads();  // staging complete (compiler drains vmcnt before barrier)
    bf16x8 af[4], bfr[4];
#pragma unroll
    for (int i = 0; i < 4; ++i) {
      af[i] = *(const bf16x8*)(As + ((wm * 4 + i) * 64 + lane) * 8);
      bfr[i] = *(const bf16x8*)(Bs + ((wn * 4 + i) * 64 + lane) * 8);
    }
#pragma unroll
    for (int i = 0; i < 4; ++i)
#pragma unroll
      for (int j = 0; j < 4; ++j)
        acc[i][j] = __builtin_amdgcn_mfma_f32_16x16x32_bf16(af[i], bfr[j], acc[i][j], 0, 0, 0);
  }

  // epilogue: d2 = t2 + s2 - 2c ; sim = exp(-sqrt(max(d2,eps)))
  // C/D layout: col = lane&15, row = (lane>>4)*4 + reg  [m89-verified]
  const int cbase = col0 + wn * 64 + (lane & 15);
  const int rbase = row0 + wm * 64 + (lane >> 4) * 4;
  float ss[4];
#pragma unroll
  for (int j = 0; j < 4; ++j) ss[j] = ssq[cbase + j * 16];
#pragma unroll
  for (int i = 0; i < 4; ++i) {
#pragma unroll
    for (int r = 0; r < 4; ++r) {
      const int row = rbase + i * 16 + r;
      const float t2 = tsq[row];
#pragma unroll
      for (int j = 0; j < 4; ++j) {
        float d2 = t2 + ss[j] - 2.0f * acc[i][j][r];
        float sim = expf(-sqrtf(fmaxf(d2, EPSF)));
        if (WRITE_BF16) {
          simU[(size_t)row * 4096 + cbase + j * 16] = bf16_rne(sim);
        } else {
          outF[(size_t)row * 4096 + cbase + j * 16] = sim;
        }
      }
    }
  }
}

// ---------------- stage 4a: row L1 normalize from bf16 unnorm -> f32 out ----------------
__global__ __launch_bounds__(256) void k_norm_bf16(const unsigned short* __restrict__ simU,
                                                   float* __restrict__ out) {
  const size_t base = (size_t)blockIdx.x * 4096;
  const int tid = threadIdx.x;
  float f[16];
  float s = 0.f;
#pragma unroll
  for (int i = 0; i < 4; ++i) {
    ushort4 v = *(const ushort4*)(simU + base + (size_t)(tid * 4 + i * 1024));
    f[4 * i + 0] = bf16_to_f32(v.x);
    f[4 * i + 1] = bf16_to_f32(v.y);
    f[4 * i + 2] = bf16_to_f32(v.z);
    f[4 * i + 3] = bf16_to_f32(v.w);
    s += f[4 * i + 0] + f[4 * i + 1] + f[4 * i + 2] + f[4 * i + 3];
  }
  s = block_reduce_sum_256(s);
  const float inv = 1.0f / fmaxf(s, EPSF);
#pragma unroll
  for (int i = 0; i < 4; ++i) {
    float4 r;
    r.x = f[4 * i + 0] * inv;
    r.y = f[4 * i + 1] * inv;
    r.z = f[4 * i + 2] * inv;
    r.w = f[4 * i + 3] * inv;
    *(float4*)(out + base + (size_t)(tid * 4 + i * 1024)) = r;
  }
}

// ---------------- stage 4b: fallback in-place f32 normalize ----------------
__global__ __launch_bounds__(256) void k_norm_f32(float* __restrict__ out) {
  const size_t base = (size_t)blockIdx.x * 4096;
  const int tid = threadIdx.x;
  float4 v[4];
  float s = 0.f;
#pragma unroll
  for (int i = 0; i < 4; ++i) {
    v[i] = *(const float4*)(out + base + (size_t)(tid * 4 + i * 1024));
    s += v[i].x + v[i].y + v[i].z + v[i].w;
  }
  s = block_reduce_sum_256(s);
  const float inv = 1.0f / fmaxf(s, EPSF);
#pragma unroll
  for (int i = 0; i < 4; ++i) {
    float4 r;
    r.x = v[i].x * inv;
    r.y = v[i].y * inv;
    r.z = v[i].z * inv;
    r.w = v[i].w * inv;
    *(float4*)(out + base + (size_t)(tid * 4 + i * 1024)) = r;
  }
}

extern "C" void kernel_launch(void* const* d_in, const int* in_sizes, int n_in,
                              void* d_out, int out_size, void* d_ws, size_t ws_size,
                              hipStream_t stream) {
  const float* m = (const float*)d_in[0];        // [4096,32,512]
  const float* om = (const float*)d_in[1];       // [32,256,512]
  const int* src_mask = (const int*)d_in[2];     // [4096,1,32]
  const int* tgt_mask = (const int*)d_in[3];     // [32,256,256]
  float* out = (float*)d_out;                    // [32,256,4096]

  float* ws = (float*)d_ws;
  float* ssq = ws;                                         // 4096 f32
  float* tsq = ssq + 4096;                                 // 8192 f32
  unsigned short* srcRb = (unsigned short*)(tsq + 8192);   // 4096*512 bf16
  unsigned short* tgtRb = srcRb + 4096 * 512;              // 8192*512 bf16
  unsigned short* simU = tgtRb + (size_t)8192 * 512;       // 8192*4096 bf16

  const size_t need_bf16 = (size_t)(4096 + 8192) * 4 +
                           ((size_t)4096 * 512 + (size_t)8192 * 512) * 2 +
                           (size_t)8192 * 4096 * 2;
  const bool use_bf16_out = ws_size >= need_bf16;

  k_src_readout<<<4096, 256, 0, stream>>>(m, src_mask, srcRb, ssq);
  k_tgt_readout<<<dim3(32, 4, 4), 256, 0, stream>>>(om, tgt_mask, tgtRb);
  k_rowsq_bf16<<<8192, 256, 0, stream>>>(tgtRb, tsq);
  if (use_bf16_out) {
    k_cross_mfma<1><<<dim3(32, 64), 256, 0, stream>>>(tgtRb, srcRb, tsq, ssq, simU, out);
    k_norm_bf16<<<8192, 256, 0, stream>>>(simU, out);
  } else {
    k_cross_mfma<0><<<dim3(32, 64), 256, 0, stream>>>(tgtRb, srcRb, tsq, ssq, simU, out);
    k_norm_f32<<<8192, 256, 0, stream>>>(out);
  }
}

// Round 6
// 201.079 us; speedup vs baseline: 1.1087x; 1.0629x over previous
//
#include <hip/hip_runtime.h>
#include <math.h>

#define EPSF 1e-12f

typedef short bf16x8 __attribute__((ext_vector_type(8)));
typedef float f32x4 __attribute__((ext_vector_type(4)));

__device__ __forceinline__ void gload_lds16(const void* g, void* l) {
  __builtin_amdgcn_global_load_lds(
      (const __attribute__((address_space(1))) unsigned int*)g,
      (__attribute__((address_space(3))) unsigned int*)l, 16, 0, 0);
}

__device__ __forceinline__ unsigned short bf16_rne(float f) {
  unsigned int u = __float_as_uint(f);
  u += 0x7fffu + ((u >> 16) & 1u);
  return (unsigned short)(u >> 16);
}

__device__ __forceinline__ float bf16_to_f32(unsigned short h) {
  return __uint_as_float((unsigned int)h << 16);
}

// ---------------- block reduce (256 threads, wave64) ----------------
__device__ __forceinline__ float block_reduce_sum_256(float v) {
#pragma unroll
  for (int o = 32; o > 0; o >>= 1) v += __shfl_down(v, o, 64);
  __shared__ float ws4[4];
  const int lane = threadIdx.x & 63;
  const int w = threadIdx.x >> 6;
  if (lane == 0) ws4[w] = v;
  __syncthreads();
  if (threadIdx.x == 0) ws4[0] = ws4[0] + ws4[1] + ws4[2] + ws4[3];
  __syncthreads();
  return ws4[0];
}

// ---------------- stage 1: src readout -> bf16 [4096,512] row-major + row sq-norm ----------------
__global__ __launch_bounds__(256) void k_src_readout(const float* __restrict__ m,
                                                     const int* __restrict__ src_mask,
                                                     unsigned short* __restrict__ srcRb,
                                                     float* __restrict__ ssq) {
  const int b = blockIdx.x;
  __shared__ int msk[32];
  __shared__ float s_inv;
  const int tid = threadIdx.x;
  if (tid < 32) msk[tid] = src_mask[b * 32 + tid];
  __syncthreads();
  if (tid == 0) {
    float c = 0.f;
    for (int s = 0; s < 32; ++s) c += (float)msk[s];
    s_inv = 1.0f / fmaxf(c, EPSF);
  }
  __syncthreads();
  const float inv = s_inv;
  const float* mb = m + (size_t)b * (32 * 512) + 2 * tid;
  float ax = 0.f, ay = 0.f;
  for (int s = 0; s < 32; ++s) {
    if (msk[s] != 0) {
      float2 v = *(const float2*)(mb + s * 512);
      ax += v.x;
      ay += v.y;
    }
  }
  ushort2 o;
  o.x = bf16_rne(ax * inv);
  o.y = bf16_rne(ay * inv);
  *(ushort2*)(srcRb + (size_t)b * 512 + 2 * tid) = o;
  float fx = bf16_to_f32(o.x), fy = bf16_to_f32(o.y);
  float s = fx * fx + fy * fy;
  s = block_reduce_sum_256(s);
  if (tid == 0) ssq[b] = s;
}

// ---------------- stage 2: tgt readout -> bf16 FRAGMENT-ORDER A' ----------------
// A'frag layout (shorts): elem (row r, col d) lives at
//   (((r>>4)*16 + (d>>5))*64 + ((d>>3)&3)*16 + (r&15))*8 + (d&7)
// i.e. per 16-row block g and K-step kt: 64 lanes x 8 shorts, lane = ((d>>3)&3)*16 + (r&15).
// This is exactly the mfma_16x16x32 A-fragment order, so cross reads 1KB contiguous per wave.
#define TR_LDW 257
__global__ __launch_bounds__(256) void k_tgt_readout(const float* __restrict__ om,
                                                     const int* __restrict__ tgt_mask,
                                                     unsigned short* __restrict__ Afrag) {
  const int b = blockIdx.x, tt = blockIdx.y, dt = blockIdx.z;
  const int t0 = tt * 64, d0 = dt * 128;
  __shared__ float wm[64 * TR_LDW];
  __shared__ float cpart[256];
  __shared__ float s_inv[64];
  const int tid = threadIdx.x;
  const int* mbase = tgt_mask + ((size_t)(b * 256 + t0)) * 256;
  for (int i = 0; i < 64; ++i) {
    int idx = tid + 256 * i;
    wm[(idx >> 8) * TR_LDW + (idx & 255)] = (float)mbase[idx];
  }
  __syncthreads();
  {
    const int r = tid >> 2, q = tid & 3;
    float c = 0.f;
    for (int u = 0; u < 64; ++u) c += wm[r * TR_LDW + q * 64 + u];
    cpart[tid] = c;
  }
  __syncthreads();
  if (tid < 64) {
    float c = cpart[4 * tid] + cpart[4 * tid + 1] + cpart[4 * tid + 2] + cpart[4 * tid + 3];
    s_inv[tid] = 1.0f / fmaxf(c, EPSF);
  }
  __syncthreads();
  const int tx = tid & 31, ty = tid >> 5;
  float4 acc[8];
#pragma unroll
  for (int j = 0; j < 8; ++j) acc[j] = make_float4(0.f, 0.f, 0.f, 0.f);
  const float* ob = om + (size_t)b * 256 * 512 + d0 + tx * 4;
  for (int u = 0; u < 256; ++u) {
    float4 o = *(const float4*)(ob + (size_t)u * 512);
#pragma unroll
    for (int j = 0; j < 8; ++j) {
      float w = wm[(ty * 8 + j) * TR_LDW + u];
      acc[j].x += o.x * w;
      acc[j].y += o.y * w;
      acc[j].z += o.z * w;
      acc[j].w += o.w * w;
    }
  }
  const int d = d0 + tx * 4;
#pragma unroll
  for (int j = 0; j < 8; ++j) {
    const int t = ty * 8 + j;
    const int r = b * 256 + t0 + t;
    const float inv = s_inv[t];
    ushort4 v;
    v.x = bf16_rne(acc[j].x * inv);
    v.y = bf16_rne(acc[j].y * inv);
    v.z = bf16_rne(acc[j].z * inv);
    v.w = bf16_rne(acc[j].w * inv);
    const size_t off = ((size_t)(((r >> 4) * 16 + (d >> 5)) * 64 + ((d >> 3) & 3) * 16 + (r & 15))) * 8 + (d & 7);
    *(ushort4*)(Afrag + off) = v;
  }
}

// ---------------- stage 2b: row squared norms from fragment-order A' ----------------
__global__ __launch_bounds__(256) void k_rowsq_frag(const unsigned short* __restrict__ Afrag,
                                                    float* __restrict__ sq) {
  const int r = blockIdx.x;
  const int tid = threadIdx.x;
  const int g = r >> 4, rl = r & 15;
  const int d = 2 * tid;
  const size_t off = ((size_t)((g * 16 + (d >> 5)) * 64 + ((d >> 3) & 3) * 16 + rl)) * 8 + (d & 7);
  ushort2 v = *(const ushort2*)(Afrag + off);
  float fx = bf16_to_f32(v.x), fy = bf16_to_f32(v.y);
  float s = fx * fx + fy * fy;
  s = block_reduce_sum_256(s);
  if (tid == 0) sq[r] = s;
}

// ---------------- stage 3: cross GEMM — B-stationary LDS, A streamed, NO K-loop barriers ----------------
// C[M=8192, N=4096], K=512. Block = 512 rows x 64 cols, 512 threads (8 waves on M).
// B-panel 64x512 bf16 staged ONCE into LDS in fragment order (64 KB); A read global
// in fragment order (1KB coalesced per wave-load). 16 K-steps, 16 MFMA each, zero barriers.
__global__ __launch_bounds__(512, 4) void k_cross_mfma(
    const unsigned short* __restrict__ Afrag, const unsigned short* __restrict__ B,
    const float* __restrict__ tsq, const float* __restrict__ ssq,
    float* __restrict__ out) {
  __shared__ unsigned short Bs[64 * 512];  // chunk c = cb*16+kt : 64 lanes x 8 shorts
  const int tid = threadIdx.x;
  const int lane = tid & 63, w = tid >> 6;  // w = 0..7 (row-wave)
  const int row0 = blockIdx.y * 512, col0 = blockIdx.x * 64;
  const int lr = lane & 15, lkh = lane >> 4;

  // ---- stage B once: 64 chunks of 1KB, 8 per wave ----
#pragma unroll
  for (int t = 0; t < 8; ++t) {
    const int c = w * 8 + t;
    const int cb = c >> 4, kt = c & 15;
    gload_lds16(B + (size_t)(col0 + cb * 16 + lr) * 512 + kt * 32 + lkh * 8,
                Bs + (size_t)c * 512);
  }

  f32x4 acc[4][4];
#pragma unroll
  for (int i = 0; i < 4; ++i)
#pragma unroll
    for (int j = 0; j < 4; ++j) acc[i][j] = (f32x4){0.f, 0.f, 0.f, 0.f};

  __syncthreads();  // B staged (compiler drains vmcnt before barrier)

  // ---- K-loop: no barriers; compiler pipelines global A loads freely ----
  const unsigned short* ap = Afrag + ((size_t)(row0 >> 4) + w * 4) * (16 * 64 * 8);
#pragma unroll
  for (int kt = 0; kt < 16; ++kt) {
    bf16x8 af[4], bfr[4];
#pragma unroll
    for (int i = 0; i < 4; ++i)
      af[i] = *(const bf16x8*)(ap + (((size_t)i * 16 + kt) * 64 + lane) * 8);
#pragma unroll
    for (int j = 0; j < 4; ++j)
      bfr[j] = *(const bf16x8*)(Bs + ((j * 16 + kt) * 64 + lane) * 8);
#pragma unroll
    for (int i = 0; i < 4; ++i)
#pragma unroll
      for (int j = 0; j < 4; ++j)
        acc[i][j] = __builtin_amdgcn_mfma_f32_16x16x32_bf16(af[i], bfr[j], acc[i][j], 0, 0, 0);
  }

  // ---- epilogue: d2 = t2 + s2 - 2c ; sim = exp(-sqrt(max(d2,eps))) ----
  // C/D layout: col = lane&15, row = (lane>>4)*4 + reg  [m89-verified]
  const int cbase = col0 + (lane & 15);
  const int rbase = row0 + w * 64 + (lane >> 4) * 4;
  float ss[4];
#pragma unroll
  for (int j = 0; j < 4; ++j) ss[j] = ssq[cbase + j * 16];
#pragma unroll
  for (int i = 0; i < 4; ++i) {
#pragma unroll
    for (int r = 0; r < 4; ++r) {
      const int row = rbase + i * 16 + r;
      const float t2 = tsq[row];
      float* op = out + (size_t)row * 4096 + cbase;
#pragma unroll
      for (int j = 0; j < 4; ++j) {
        float d2 = t2 + ss[j] - 2.0f * acc[i][j][r];
        op[j * 16] = expf(-sqrtf(fmaxf(d2, EPSF)));
      }
    }
  }
}

// ---------------- stage 4: row L1 normalize (in-place f32) ----------------
__global__ __launch_bounds__(256) void k_norm(float* __restrict__ out) {
  const size_t base = (size_t)blockIdx.x * 4096;
  const int tid = threadIdx.x;
  float4 v[4];
  float s = 0.f;
#pragma unroll
  for (int i = 0; i < 4; ++i) {
    v[i] = *(const float4*)(out + base + (size_t)(tid * 4 + i * 1024));
    s += v[i].x + v[i].y + v[i].z + v[i].w;
  }
  s = block_reduce_sum_256(s);
  const float inv = 1.0f / fmaxf(s, EPSF);
#pragma unroll
  for (int i = 0; i < 4; ++i) {
    float4 r;
    r.x = v[i].x * inv;
    r.y = v[i].y * inv;
    r.z = v[i].z * inv;
    r.w = v[i].w * inv;
    *(float4*)(out + base + (size_t)(tid * 4 + i * 1024)) = r;
  }
}

extern "C" void kernel_launch(void* const* d_in, const int* in_sizes, int n_in,
                              void* d_out, int out_size, void* d_ws, size_t ws_size,
                              hipStream_t stream) {
  const float* m = (const float*)d_in[0];        // [4096,32,512]
  const float* om = (const float*)d_in[1];       // [32,256,512]
  const int* src_mask = (const int*)d_in[2];     // [4096,1,32]
  const int* tgt_mask = (const int*)d_in[3];     // [32,256,256]
  float* out = (float*)d_out;                    // [32,256,4096]

  float* ws = (float*)d_ws;
  float* ssq = ws;                                         // 4096 f32
  float* tsq = ssq + 4096;                                 // 8192 f32
  unsigned short* srcRb = (unsigned short*)(tsq + 8192);   // 4096*512 bf16 row-major
  unsigned short* Afrag = srcRb + 4096 * 512;              // 8192*512 bf16 fragment-order

  k_src_readout<<<4096, 256, 0, stream>>>(m, src_mask, srcRb, ssq);
  k_tgt_readout<<<dim3(32, 4, 4), 256, 0, stream>>>(om, tgt_mask, Afrag);
  k_rowsq_frag<<<8192, 256, 0, stream>>>(Afrag, tsq);
  k_cross_mfma<<<dim3(64, 16), 512, 0, stream>>>(Afrag, srcRb, tsq, ssq, out);
  k_norm<<<8192, 256, 0, stream>>>(out);
}

// Round 7
// 171.114 us; speedup vs baseline: 1.3028x; 1.1751x over previous
//
#include <hip/hip_runtime.h>
#include <math.h>

#define EPSF 1e-12f

typedef short bf16x8 __attribute__((ext_vector_type(8)));
typedef float f32x4 __attribute__((ext_vector_type(4)));

__device__ __forceinline__ void gload_lds16(const void* g, void* l) {
  __builtin_amdgcn_global_load_lds(
      (const __attribute__((address_space(1))) unsigned int*)g,
      (__attribute__((address_space(3))) unsigned int*)l, 16, 0, 0);
}

__device__ __forceinline__ unsigned short bf16_rne(float f) {
  unsigned int u = __float_as_uint(f);
  u += 0x7fffu + ((u >> 16) & 1u);
  return (unsigned short)(u >> 16);
}

__device__ __forceinline__ float bf16_to_f32(unsigned short h) {
  return __uint_as_float((unsigned int)h << 16);
}

// ---------------- block reduce (256 threads, wave64) ----------------
__device__ __forceinline__ float block_reduce_sum_256(float v) {
#pragma unroll
  for (int o = 32; o > 0; o >>= 1) v += __shfl_down(v, o, 64);
  __shared__ float ws4[4];
  const int lane = threadIdx.x & 63;
  const int w = threadIdx.x >> 6;
  if (lane == 0) ws4[w] = v;
  __syncthreads();
  if (threadIdx.x == 0) ws4[0] = ws4[0] + ws4[1] + ws4[2] + ws4[3];
  __syncthreads();
  return ws4[0];
}

// ---------------- stage 1: src readout (float4, 2 batches/block) ----------------
__global__ __launch_bounds__(256) void k_src_readout(const float* __restrict__ m,
                                                     const int* __restrict__ src_mask,
                                                     unsigned short* __restrict__ srcRb,
                                                     float* __restrict__ ssq) {
  const int tid = threadIdx.x;
  const int sub = tid >> 7, t = tid & 127;
  const int b = blockIdx.x * 2 + sub;
  __shared__ int msk[2][32];
  __shared__ float sinv[2];
  __shared__ float red[4];
  if (t < 32) msk[sub][t] = src_mask[b * 32 + t];
  __syncthreads();
  if (t == 0) {
    float c = 0.f;
    for (int s = 0; s < 32; ++s) c += (float)msk[sub][s];
    sinv[sub] = 1.0f / fmaxf(c, EPSF);
  }
  __syncthreads();
  const float inv = sinv[sub];
  const float4* mb = (const float4*)(m + (size_t)b * (32 * 512)) + t;
  float ax = 0.f, ay = 0.f, az = 0.f, aw = 0.f;
  for (int s = 0; s < 32; ++s) {
    if (msk[sub][s] != 0) {
      float4 v = mb[s * 128];
      ax += v.x; ay += v.y; az += v.z; aw += v.w;
    }
  }
  ushort4 o;
  o.x = bf16_rne(ax * inv);
  o.y = bf16_rne(ay * inv);
  o.z = bf16_rne(az * inv);
  o.w = bf16_rne(aw * inv);
  *(ushort4*)(srcRb + (size_t)b * 512 + t * 4) = o;
  // squared norm of the bf16-rounded readout
  float fx = bf16_to_f32(o.x), fy = bf16_to_f32(o.y);
  float fz = bf16_to_f32(o.z), fw = bf16_to_f32(o.w);
  float s = fx * fx + fy * fy + fz * fz + fw * fw;
#pragma unroll
  for (int oo = 32; oo > 0; oo >>= 1) s += __shfl_down(s, oo, 64);
  if ((tid & 63) == 0) red[tid >> 6] = s;
  __syncthreads();
  if (t == 0) ssq[b] = red[sub * 2] + red[sub * 2 + 1];
}

// ---------------- stage 2: tgt readout via MFMA mask-GEMM -> fragment-order A' ----------------
// Per block: batch b, d-quarter dq (128 d), t-half th (128 t). K = 256 (u), chunks of 64.
// tgtR[t][d] = (sum_u mask[t][u]*om[u][d]) * (1/count[t]); mask 0/1 exact in bf16.
// Swapped mfma(om_frag, W_frag): acc regs index d (consecutive) -> ushort4 stores to Afrag.
// A'frag layout (shorts): elem (row r, col d) at
//   (((r>>4)*16 + (d>>5))*64 + ((d>>3)&3)*16 + (r&15))*8 + (d&7)
#define WST 72  // LDS stride in shorts (144 B = 36 dwords -> 2-way banks, free)
__global__ __launch_bounds__(512) void k_tgt_readout_mfma(
    const float* __restrict__ om, const int* __restrict__ tgt_mask,
    unsigned short* __restrict__ Afrag) {
  const int b = blockIdx.x, dq = blockIdx.y, th = blockIdx.z;
  const int d0 = dq * 128, t0 = th * 128;
  __shared__ unsigned short Wb[128 * WST];   // [t_local][u_local] bf16 0/1
  __shared__ unsigned short omT[128 * WST];  // [d_local][u_local] bf16
  __shared__ float cntp[128 * 4];
  __shared__ float cnt_inv[128];
  const int tid = threadIdx.x;
  const int lane = tid & 63, w = tid >> 6;
  const int* mbase = tgt_mask + (size_t)b * 65536 + (size_t)t0 * 256;

  // counts: thread (t = tid>>2, quarter q) sums 64 ints
  {
    const int t = tid >> 2, q = tid & 3;
    const int* mp = mbase + t * 256 + q * 64;
    int c = 0;
#pragma unroll
    for (int k = 0; k < 16; ++k) {
      int4 v = *(const int4*)(mp + 4 * k);
      c += v.x + v.y + v.z + v.w;
    }
    cntp[t * 4 + q] = (float)c;
  }
  __syncthreads();
  if (tid < 128) {
    float c = cntp[tid * 4] + cntp[tid * 4 + 1] + cntp[tid * 4 + 2] + cntp[tid * 4 + 3];
    cnt_inv[tid] = 1.0f / fmaxf(c, EPSF);
  }

  f32x4 acc[8];
#pragma unroll
  for (int di = 0; di < 8; ++di) acc[di] = (f32x4){0.f, 0.f, 0.f, 0.f};

  for (int uc = 0; uc < 4; ++uc) {
    const int ub = uc * 64;
    __syncthreads();  // previous chunk's reads done (also covers cnt_inv visibility)
    // stage mask chunk as bf16 0/1: thread t=tid>>2, ul0=(tid&3)*16
    {
      const int t = tid >> 2, ul0 = (tid & 3) * 16;
      const int* mp = mbase + t * 256 + ub + ul0;
      unsigned short* wp = Wb + t * WST + ul0;
#pragma unroll
      for (int k = 0; k < 4; ++k) {
        int4 v = *(const int4*)(mp + 4 * k);
        ushort4 h;
        h.x = v.x ? 0x3F80 : 0;
        h.y = v.y ? 0x3F80 : 0;
        h.z = v.z ? 0x3F80 : 0;
        h.w = v.w ? 0x3F80 : 0;
        *(ushort4*)(wp + 4 * k) = h;
      }
    }
    // stage om chunk transposed: 64 u x 128 d -> omT[d][u]
    {
#pragma unroll
      for (int k = 0; k < 4; ++k) {
        const int idx = tid + 512 * k;  // 0..2047
        const int u = idx >> 5, dl = (idx & 31) * 4;
        float4 v = *(const float4*)(om + (size_t)b * 131072 + (size_t)(ub + u) * 512 + d0 + dl);
        omT[(dl + 0) * WST + u] = bf16_rne(v.x);
        omT[(dl + 1) * WST + u] = bf16_rne(v.y);
        omT[(dl + 2) * WST + u] = bf16_rne(v.z);
        omT[(dl + 3) * WST + u] = bf16_rne(v.w);
      }
    }
    __syncthreads();
#pragma unroll
    for (int kt2 = 0; kt2 < 2; ++kt2) {
      const int ko = kt2 * 32 + (lane >> 4) * 8;
      bf16x8 wf = *(const bf16x8*)(Wb + (w * 16 + (lane & 15)) * WST + ko);
      bf16x8 of[8];
#pragma unroll
      for (int di = 0; di < 8; ++di)
        of[di] = *(const bf16x8*)(omT + (di * 16 + (lane & 15)) * WST + ko);
#pragma unroll
      for (int di = 0; di < 8; ++di)
        acc[di] = __builtin_amdgcn_mfma_f32_16x16x32_bf16(of[di], wf, acc[di], 0, 0, 0);
    }
  }

  // epilogue: D[d][t]: reg-side = om row = d (consecutive), lane&15-side = W row = t
  const int tl = w * 16 + (lane & 15);
  const int rT = b * 256 + t0 + tl;
  const float inv = cnt_inv[tl];
#pragma unroll
  for (int di = 0; di < 8; ++di) {
    const int d = d0 + di * 16 + (lane >> 4) * 4;  // 4 consecutive d (d&7 in {0,4})
    ushort4 o;
    o.x = bf16_rne(acc[di][0] * inv);
    o.y = bf16_rne(acc[di][1] * inv);
    o.z = bf16_rne(acc[di][2] * inv);
    o.w = bf16_rne(acc[di][3] * inv);
    const size_t off =
        (((size_t)(rT >> 4) * 16 + (d >> 5)) * 64 + ((d >> 3) & 3) * 16 + (rT & 15)) * 8 + (d & 7);
    *(ushort4*)(Afrag + off) = o;
  }
}

// ---------------- stage 2b: row squared norms from fragment-order A' ----------------
__global__ __launch_bounds__(256) void k_rowsq_frag(const unsigned short* __restrict__ Afrag,
                                                    float* __restrict__ sq) {
  const int r = blockIdx.x;
  const int tid = threadIdx.x;
  const int g = r >> 4, rl = r & 15;
  const int d = 2 * tid;
  const size_t off = ((size_t)((g * 16 + (d >> 5)) * 64 + ((d >> 3) & 3) * 16 + rl)) * 8 + (d & 7);
  ushort2 v = *(const ushort2*)(Afrag + off);
  float fx = bf16_to_f32(v.x), fy = bf16_to_f32(v.y);
  float s = fx * fx + fy * fy;
  s = block_reduce_sum_256(s);
  if (tid == 0) sq[r] = s;
}

// ---------------- stage 3: cross GEMM — B-stationary LDS, A streamed, NO K-loop barriers ----------------
__global__ __launch_bounds__(512, 4) void k_cross_mfma(
    const unsigned short* __restrict__ Afrag, const unsigned short* __restrict__ B,
    const float* __restrict__ tsq, const float* __restrict__ ssq,
    float* __restrict__ out) {
  __shared__ unsigned short Bs[64 * 512];  // chunk c = cb*16+kt : 64 lanes x 8 shorts
  const int tid = threadIdx.x;
  const int lane = tid & 63, w = tid >> 6;  // w = 0..7 (row-wave)
  const int row0 = blockIdx.y * 512, col0 = blockIdx.x * 64;
  const int lr = lane & 15, lkh = lane >> 4;

  // ---- stage B once: 64 chunks of 1KB, 8 per wave ----
#pragma unroll
  for (int t = 0; t < 8; ++t) {
    const int c = w * 8 + t;
    const int cb = c >> 4, kt = c & 15;
    gload_lds16(B + (size_t)(col0 + cb * 16 + lr) * 512 + kt * 32 + lkh * 8,
                Bs + (size_t)c * 512);
  }

  f32x4 acc[4][4];
#pragma unroll
  for (int i = 0; i < 4; ++i)
#pragma unroll
    for (int j = 0; j < 4; ++j) acc[i][j] = (f32x4){0.f, 0.f, 0.f, 0.f};

  __syncthreads();  // B staged (compiler drains vmcnt before barrier)

  // ---- K-loop: no barriers; compiler pipelines global A loads freely ----
  const unsigned short* ap = Afrag + ((size_t)(row0 >> 4) + w * 4) * (16 * 64 * 8);
#pragma unroll
  for (int kt = 0; kt < 16; ++kt) {
    bf16x8 af[4], bfr[4];
#pragma unroll
    for (int i = 0; i < 4; ++i)
      af[i] = *(const bf16x8*)(ap + (((size_t)i * 16 + kt) * 64 + lane) * 8);
#pragma unroll
    for (int j = 0; j < 4; ++j)
      bfr[j] = *(const bf16x8*)(Bs + ((j * 16 + kt) * 64 + lane) * 8);
#pragma unroll
    for (int i = 0; i < 4; ++i)
#pragma unroll
      for (int j = 0; j < 4; ++j)
        acc[i][j] = __builtin_amdgcn_mfma_f32_16x16x32_bf16(af[i], bfr[j], acc[i][j], 0, 0, 0);
  }

  // ---- epilogue: d2 = t2 + s2 - 2c ; sim = exp(-sqrt(max(d2,eps))) ----
  const int cbase = col0 + (lane & 15);
  const int rbase = row0 + w * 64 + (lane >> 4) * 4;
  float ss[4];
#pragma unroll
  for (int j = 0; j < 4; ++j) ss[j] = ssq[cbase + j * 16];
#pragma unroll
  for (int i = 0; i < 4; ++i) {
#pragma unroll
    for (int r = 0; r < 4; ++r) {
      const int row = rbase + i * 16 + r;
      const float t2 = tsq[row];
      float* op = out + (size_t)row * 4096 + cbase;
#pragma unroll
      for (int j = 0; j < 4; ++j) {
        float d2 = t2 + ss[j] - 2.0f * acc[i][j][r];
        op[j * 16] = expf(-sqrtf(fmaxf(d2, EPSF)));
      }
    }
  }
}

// ---------------- stage 4: row L1 normalize (in-place f32) ----------------
__global__ __launch_bounds__(256) void k_norm(float* __restrict__ out) {
  const size_t base = (size_t)blockIdx.x * 4096;
  const int tid = threadIdx.x;
  float4 v[4];
  float s = 0.f;
#pragma unroll
  for (int i = 0; i < 4; ++i) {
    v[i] = *(const float4*)(out + base + (size_t)(tid * 4 + i * 1024));
    s += v[i].x + v[i].y + v[i].z + v[i].w;
  }
  s = block_reduce_sum_256(s);
  const float inv = 1.0f / fmaxf(s, EPSF);
#pragma unroll
  for (int i = 0; i < 4; ++i) {
    float4 r;
    r.x = v[i].x * inv;
    r.y = v[i].y * inv;
    r.z = v[i].z * inv;
    r.w = v[i].w * inv;
    *(float4*)(out + base + (size_t)(tid * 4 + i * 1024)) = r;
  }
}

extern "C" void kernel_launch(void* const* d_in, const int* in_sizes, int n_in,
                              void* d_out, int out_size, void* d_ws, size_t ws_size,
                              hipStream_t stream) {
  const float* m = (const float*)d_in[0];        // [4096,32,512]
  const float* om = (const float*)d_in[1];       // [32,256,512]
  const int* src_mask = (const int*)d_in[2];     // [4096,1,32]
  const int* tgt_mask = (const int*)d_in[3];     // [32,256,256]
  float* out = (float*)d_out;                    // [32,256,4096]

  float* ws = (float*)d_ws;
  float* ssq = ws;                                         // 4096 f32
  float* tsq = ssq + 4096;                                 // 8192 f32
  unsigned short* srcRb = (unsigned short*)(tsq + 8192);   // 4096*512 bf16 row-major
  unsigned short* Afrag = srcRb + 4096 * 512;              // 8192*512 bf16 fragment-order

  k_src_readout<<<2048, 256, 0, stream>>>(m, src_mask, srcRb, ssq);
  k_tgt_readout_mfma<<<dim3(32, 4, 2), 512, 0, stream>>>(om, tgt_mask, Afrag);
  k_rowsq_frag<<<8192, 256, 0, stream>>>(Afrag, tsq);
  k_cross_mfma<<<dim3(64, 16), 512, 0, stream>>>(Afrag, srcRb, tsq, ssq, out);
  k_norm<<<8192, 256, 0, stream>>>(out);
}

// Round 8
// 166.031 us; speedup vs baseline: 1.3427x; 1.0306x over previous
//
#include <hip/hip_runtime.h>
#include <math.h>

#define EPSF 1e-12f

typedef short bf16x8 __attribute__((ext_vector_type(8)));
typedef float f32x4 __attribute__((ext_vector_type(4)));

__device__ __forceinline__ void gload_lds16(const void* g, void* l) {
  __builtin_amdgcn_global_load_lds(
      (const __attribute__((address_space(1))) unsigned int*)g,
      (__attribute__((address_space(3))) unsigned int*)l, 16, 0, 0);
}

__device__ __forceinline__ unsigned short bf16_rne(float f) {
  unsigned int u = __float_as_uint(f);
  u += 0x7fffu + ((u >> 16) & 1u);
  return (unsigned short)(u >> 16);
}

__device__ __forceinline__ float bf16_to_f32(unsigned short h) {
  return __uint_as_float((unsigned int)h << 16);
}

// ---------------- block reduce (256 threads, wave64) ----------------
__device__ __forceinline__ float block_reduce_sum_256(float v) {
#pragma unroll
  for (int o = 32; o > 0; o >>= 1) v += __shfl_down(v, o, 64);
  __shared__ float ws4[4];
  const int lane = threadIdx.x & 63;
  const int w = threadIdx.x >> 6;
  if (lane == 0) ws4[w] = v;
  __syncthreads();
  if (threadIdx.x == 0) ws4[0] = ws4[0] + ws4[1] + ws4[2] + ws4[3];
  __syncthreads();
  return ws4[0];
}

// ---------------- stage 1: src readout (float4, 2 batches/block) ----------------
__global__ __launch_bounds__(256) void k_src_readout(const float* __restrict__ m,
                                                     const int* __restrict__ src_mask,
                                                     unsigned short* __restrict__ srcRb,
                                                     float* __restrict__ ssq) {
  const int tid = threadIdx.x;
  const int sub = tid >> 7, t = tid & 127;
  const int b = blockIdx.x * 2 + sub;
  __shared__ int msk[2][32];
  __shared__ float sinv[2];
  __shared__ float red[4];
  if (t < 32) msk[sub][t] = src_mask[b * 32 + t];
  __syncthreads();
  if (t == 0) {
    float c = 0.f;
    for (int s = 0; s < 32; ++s) c += (float)msk[sub][s];
    sinv[sub] = 1.0f / fmaxf(c, EPSF);
  }
  __syncthreads();
  const float inv = sinv[sub];
  const float4* mb = (const float4*)(m + (size_t)b * (32 * 512)) + t;
  float ax = 0.f, ay = 0.f, az = 0.f, aw = 0.f;
  for (int s = 0; s < 32; ++s) {
    if (msk[sub][s] != 0) {
      float4 v = mb[s * 128];
      ax += v.x; ay += v.y; az += v.z; aw += v.w;
    }
  }
  ushort4 o;
  o.x = bf16_rne(ax * inv);
  o.y = bf16_rne(ay * inv);
  o.z = bf16_rne(az * inv);
  o.w = bf16_rne(aw * inv);
  *(ushort4*)(srcRb + (size_t)b * 512 + t * 4) = o;
  float fx = bf16_to_f32(o.x), fy = bf16_to_f32(o.y);
  float fz = bf16_to_f32(o.z), fw = bf16_to_f32(o.w);
  float s = fx * fx + fy * fy + fz * fz + fw * fw;
#pragma unroll
  for (int oo = 32; oo > 0; oo >>= 1) s += __shfl_down(s, oo, 64);
  if ((tid & 63) == 0) red[tid >> 6] = s;
  __syncthreads();
  if (t == 0) ssq[b] = red[sub * 2] + red[sub * 2 + 1];
}

// ---------------- stage 2: tgt readout via MFMA mask-GEMM -> fragment-order A' ----------------
#define WST 72
__global__ __launch_bounds__(512) void k_tgt_readout_mfma(
    const float* __restrict__ om, const int* __restrict__ tgt_mask,
    unsigned short* __restrict__ Afrag) {
  const int b = blockIdx.x, dq = blockIdx.y, th = blockIdx.z;
  const int d0 = dq * 128, t0 = th * 128;
  __shared__ unsigned short Wb[128 * WST];
  __shared__ unsigned short omT[128 * WST];
  __shared__ float cntp[128 * 4];
  __shared__ float cnt_inv[128];
  const int tid = threadIdx.x;
  const int lane = tid & 63, w = tid >> 6;
  const int* mbase = tgt_mask + (size_t)b * 65536 + (size_t)t0 * 256;

  {
    const int t = tid >> 2, q = tid & 3;
    const int* mp = mbase + t * 256 + q * 64;
    int c = 0;
#pragma unroll
    for (int k = 0; k < 16; ++k) {
      int4 v = *(const int4*)(mp + 4 * k);
      c += v.x + v.y + v.z + v.w;
    }
    cntp[t * 4 + q] = (float)c;
  }
  __syncthreads();
  if (tid < 128) {
    float c = cntp[tid * 4] + cntp[tid * 4 + 1] + cntp[tid * 4 + 2] + cntp[tid * 4 + 3];
    cnt_inv[tid] = 1.0f / fmaxf(c, EPSF);
  }

  f32x4 acc[8];
#pragma unroll
  for (int di = 0; di < 8; ++di) acc[di] = (f32x4){0.f, 0.f, 0.f, 0.f};

  for (int uc = 0; uc < 4; ++uc) {
    const int ub = uc * 64;
    __syncthreads();
    {
      const int t = tid >> 2, ul0 = (tid & 3) * 16;
      const int* mp = mbase + t * 256 + ub + ul0;
      unsigned short* wp = Wb + t * WST + ul0;
#pragma unroll
      for (int k = 0; k < 4; ++k) {
        int4 v = *(const int4*)(mp + 4 * k);
        ushort4 h;
        h.x = v.x ? 0x3F80 : 0;
        h.y = v.y ? 0x3F80 : 0;
        h.z = v.z ? 0x3F80 : 0;
        h.w = v.w ? 0x3F80 : 0;
        *(ushort4*)(wp + 4 * k) = h;
      }
    }
    {
#pragma unroll
      for (int k = 0; k < 4; ++k) {
        const int idx = tid + 512 * k;
        const int u = idx >> 5, dl = (idx & 31) * 4;
        float4 v = *(const float4*)(om + (size_t)b * 131072 + (size_t)(ub + u) * 512 + d0 + dl);
        omT[(dl + 0) * WST + u] = bf16_rne(v.x);
        omT[(dl + 1) * WST + u] = bf16_rne(v.y);
        omT[(dl + 2) * WST + u] = bf16_rne(v.z);
        omT[(dl + 3) * WST + u] = bf16_rne(v.w);
      }
    }
    __syncthreads();
#pragma unroll
    for (int kt2 = 0; kt2 < 2; ++kt2) {
      const int ko = kt2 * 32 + (lane >> 4) * 8;
      bf16x8 wf = *(const bf16x8*)(Wb + (w * 16 + (lane & 15)) * WST + ko);
      bf16x8 of[8];
#pragma unroll
      for (int di = 0; di < 8; ++di)
        of[di] = *(const bf16x8*)(omT + (di * 16 + (lane & 15)) * WST + ko);
#pragma unroll
      for (int di = 0; di < 8; ++di)
        acc[di] = __builtin_amdgcn_mfma_f32_16x16x32_bf16(of[di], wf, acc[di], 0, 0, 0);
    }
  }

  const int tl = w * 16 + (lane & 15);
  const int rT = b * 256 + t0 + tl;
  const float inv = cnt_inv[tl];
#pragma unroll
  for (int di = 0; di < 8; ++di) {
    const int d = d0 + di * 16 + (lane >> 4) * 4;
    ushort4 o;
    o.x = bf16_rne(acc[di][0] * inv);
    o.y = bf16_rne(acc[di][1] * inv);
    o.z = bf16_rne(acc[di][2] * inv);
    o.w = bf16_rne(acc[di][3] * inv);
    const size_t off =
        (((size_t)(rT >> 4) * 16 + (d >> 5)) * 64 + ((d >> 3) & 3) * 16 + (rT & 15)) * 8 + (d & 7);
    *(ushort4*)(Afrag + off) = o;
  }
}

// ---------------- stage 2b: row squared norms from fragment-order A' ----------------
__global__ __launch_bounds__(256) void k_rowsq_frag(const unsigned short* __restrict__ Afrag,
                                                    float* __restrict__ sq) {
  const int r = blockIdx.x;
  const int tid = threadIdx.x;
  const int g = r >> 4, rl = r & 15;
  const int d = 2 * tid;
  const size_t off = ((size_t)((g * 16 + (d >> 5)) * 64 + ((d >> 3) & 3) * 16 + rl)) * 8 + (d & 7);
  ushort2 v = *(const ushort2*)(Afrag + off);
  float fx = bf16_to_f32(v.x), fy = bf16_to_f32(v.y);
  float s = fx * fx + fy * fy;
  s = block_reduce_sum_256(s);
  if (tid == 0) sq[r] = s;
}

// ---------------- stage 3: cross GEMM — B-stationary (128 cols), A streamed, 1 barrier ----------------
// C[M=8192, N=4096], K=512. Block = 512 rows x 128 cols, 512 threads (8 row-waves),
// wave tile = 64 x 128 (4 A-frags global x 8 B-frags LDS, 32 MFMA / K-step).
// B-panel 128x512 bf16 = 128 KB LDS staged once. XCD-bijective grid decode:
// 512 blocks = 8 XCD x (2 A-panels x 32 col-tiles) -> A-panel stream stays in XCD L2.
__global__ __launch_bounds__(512, 2) void k_cross_mfma(
    const unsigned short* __restrict__ Afrag, const unsigned short* __restrict__ B,
    const float* __restrict__ tsq, const float* __restrict__ ssq,
    float* __restrict__ out) {
  __shared__ unsigned short Bs[128 * 512];  // chunk c = j*16+kt : 64 lanes x 8 shorts
  const int tid = threadIdx.x;
  const int lane = tid & 63, w = tid >> 6;  // w = 0..7 (row-wave)
  // XCD decode: xcd = bid&7 gets rows [xcd*1024, +1024)
  const int bid = blockIdx.x;
  const int xcd = bid & 7, idx = bid >> 3;
  const int row0 = (xcd * 2 + (idx >> 5)) * 512;
  const int col0 = (idx & 31) * 128;
  const int lr = lane & 15, lkh = lane >> 4;

  // ---- stage B once: 128 chunks of 1KB, 16 per wave ----
#pragma unroll
  for (int t = 0; t < 16; ++t) {
    const int c = w * 16 + t;
    const int j = c >> 4, kt = c & 15;
    gload_lds16(B + (size_t)(col0 + j * 16 + lr) * 512 + kt * 32 + lkh * 8,
                Bs + (size_t)c * 512);
  }

  f32x4 acc[4][8];
#pragma unroll
  for (int i = 0; i < 4; ++i)
#pragma unroll
    for (int j = 0; j < 8; ++j) acc[i][j] = (f32x4){0.f, 0.f, 0.f, 0.f};

  __syncthreads();  // B staged (compiler drains vmcnt before barrier)

  // ---- K-loop: no barriers; compiler pipelines global A loads freely ----
  const unsigned short* ap = Afrag + ((size_t)(row0 >> 4) + w * 4) * (16 * 64 * 8);
#pragma unroll
  for (int kt = 0; kt < 16; ++kt) {
    bf16x8 af[4], bfr[8];
#pragma unroll
    for (int i = 0; i < 4; ++i)
      af[i] = *(const bf16x8*)(ap + (((size_t)i * 16 + kt) * 64 + lane) * 8);
#pragma unroll
    for (int j = 0; j < 8; ++j)
      bfr[j] = *(const bf16x8*)(Bs + ((j * 16 + kt) * 64 + lane) * 8);
#pragma unroll
    for (int i = 0; i < 4; ++i)
#pragma unroll
      for (int j = 0; j < 8; ++j)
        acc[i][j] = __builtin_amdgcn_mfma_f32_16x16x32_bf16(af[i], bfr[j], acc[i][j], 0, 0, 0);
  }

  // ---- epilogue: d2 = t2 + s2 - 2c ; sim = exp(-sqrt(max(d2,eps))) ----
  // C/D layout: col = lane&15, row = (lane>>4)*4 + reg  [m89-verified]
  const int cbase = col0 + (lane & 15);
  const int rbase = row0 + w * 64 + (lane >> 4) * 4;
  float ss[8];
#pragma unroll
  for (int j = 0; j < 8; ++j) ss[j] = ssq[cbase + j * 16];
#pragma unroll
  for (int i = 0; i < 4; ++i) {
#pragma unroll
    for (int r = 0; r < 4; ++r) {
      const int row = rbase + i * 16 + r;
      const float t2 = tsq[row];
      float* op = out + (size_t)row * 4096 + cbase;
#pragma unroll
      for (int j = 0; j < 8; ++j) {
        float d2 = t2 + ss[j] - 2.0f * acc[i][j][r];
        op[j * 16] = expf(-sqrtf(fmaxf(d2, EPSF)));
      }
    }
  }
}

// ---------------- stage 4: row L1 normalize (in-place f32) ----------------
__global__ __launch_bounds__(256) void k_norm(float* __restrict__ out) {
  const size_t base = (size_t)blockIdx.x * 4096;
  const int tid = threadIdx.x;
  float4 v[4];
  float s = 0.f;
#pragma unroll
  for (int i = 0; i < 4; ++i) {
    v[i] = *(const float4*)(out + base + (size_t)(tid * 4 + i * 1024));
    s += v[i].x + v[i].y + v[i].z + v[i].w;
  }
  s = block_reduce_sum_256(s);
  const float inv = 1.0f / fmaxf(s, EPSF);
#pragma unroll
  for (int i = 0; i < 4; ++i) {
    float4 r;
    r.x = v[i].x * inv;
    r.y = v[i].y * inv;
    r.z = v[i].z * inv;
    r.w = v[i].w * inv;
    *(float4*)(out + base + (size_t)(tid * 4 + i * 1024)) = r;
  }
}

extern "C" void kernel_launch(void* const* d_in, const int* in_sizes, int n_in,
                              void* d_out, int out_size, void* d_ws, size_t ws_size,
                              hipStream_t stream) {
  const float* m = (const float*)d_in[0];        // [4096,32,512]
  const float* om = (const float*)d_in[1];       // [32,256,512]
  const int* src_mask = (const int*)d_in[2];     // [4096,1,32]
  const int* tgt_mask = (const int*)d_in[3];     // [32,256,256]
  float* out = (float*)d_out;                    // [32,256,4096]

  float* ws = (float*)d_ws;
  float* ssq = ws;                                         // 4096 f32
  float* tsq = ssq + 4096;                                 // 8192 f32
  unsigned short* srcRb = (unsigned short*)(tsq + 8192);   // 4096*512 bf16 row-major
  unsigned short* Afrag = srcRb + 4096 * 512;              // 8192*512 bf16 fragment-order

  k_src_readout<<<2048, 256, 0, stream>>>(m, src_mask, srcRb, ssq);
  k_tgt_readout_mfma<<<dim3(32, 4, 2), 512, 0, stream>>>(om, tgt_mask, Afrag);
  k_rowsq_frag<<<8192, 256, 0, stream>>>(Afrag, tsq);
  k_cross_mfma<<<512, 512, 0, stream>>>(Afrag, srcRb, tsq, ssq, out);
  k_norm<<<8192, 256, 0, stream>>>(out);
}

// Round 9
// 165.198 us; speedup vs baseline: 1.3495x; 1.0050x over previous
//
#include <hip/hip_runtime.h>
#include <math.h>

#define EPSF 1e-12f

typedef short bf16x8 __attribute__((ext_vector_type(8)));
typedef float f32x4 __attribute__((ext_vector_type(4)));

__device__ __forceinline__ void gload_lds16(const void* g, void* l) {
  __builtin_amdgcn_global_load_lds(
      (const __attribute__((address_space(1))) unsigned int*)g,
      (__attribute__((address_space(3))) unsigned int*)l, 16, 0, 0);
}

__device__ __forceinline__ unsigned short bf16_rne(float f) {
  unsigned int u = __float_as_uint(f);
  u += 0x7fffu + ((u >> 16) & 1u);
  return (unsigned short)(u >> 16);
}

__device__ __forceinline__ float bf16_to_f32(unsigned short h) {
  return __uint_as_float((unsigned int)h << 16);
}

// ---------------- block reduce (256 threads, wave64) ----------------
__device__ __forceinline__ float block_reduce_sum_256(float v) {
#pragma unroll
  for (int o = 32; o > 0; o >>= 1) v += __shfl_down(v, o, 64);
  __shared__ float ws4[4];
  const int lane = threadIdx.x & 63;
  const int w = threadIdx.x >> 6;
  if (lane == 0) ws4[w] = v;
  __syncthreads();
  if (threadIdx.x == 0) ws4[0] = ws4[0] + ws4[1] + ws4[2] + ws4[3];
  __syncthreads();
  return ws4[0];
}

// ---------------- stage 1: src readout (float4, 2 batches/block) ----------------
__global__ __launch_bounds__(256) void k_src_readout(const float* __restrict__ m,
                                                     const int* __restrict__ src_mask,
                                                     unsigned short* __restrict__ srcRb,
                                                     float* __restrict__ ssq) {
  const int tid = threadIdx.x;
  const int sub = tid >> 7, t = tid & 127;
  const int b = blockIdx.x * 2 + sub;
  __shared__ int msk[2][32];
  __shared__ float sinv[2];
  __shared__ float red[4];
  if (t < 32) msk[sub][t] = src_mask[b * 32 + t];
  __syncthreads();
  if (t == 0) {
    float c = 0.f;
    for (int s = 0; s < 32; ++s) c += (float)msk[sub][s];
    sinv[sub] = 1.0f / fmaxf(c, EPSF);
  }
  __syncthreads();
  const float inv = sinv[sub];
  const float4* mb = (const float4*)(m + (size_t)b * (32 * 512)) + t;
  float ax = 0.f, ay = 0.f, az = 0.f, aw = 0.f;
  for (int s = 0; s < 32; ++s) {
    if (msk[sub][s] != 0) {
      float4 v = mb[s * 128];
      ax += v.x; ay += v.y; az += v.z; aw += v.w;
    }
  }
  ushort4 o;
  o.x = bf16_rne(ax * inv);
  o.y = bf16_rne(ay * inv);
  o.z = bf16_rne(az * inv);
  o.w = bf16_rne(aw * inv);
  *(ushort4*)(srcRb + (size_t)b * 512 + t * 4) = o;
  float fx = bf16_to_f32(o.x), fy = bf16_to_f32(o.y);
  float fz = bf16_to_f32(o.z), fw = bf16_to_f32(o.w);
  float s = fx * fx + fy * fy + fz * fz + fw * fw;
#pragma unroll
  for (int oo = 32; oo > 0; oo >>= 1) s += __shfl_down(s, oo, 64);
  if ((tid & 63) == 0) red[tid >> 6] = s;
  __syncthreads();
  if (t == 0) ssq[b] = red[sub * 2] + red[sub * 2 + 1];
}

// ---------------- stage 2: tgt readout via MFMA mask-GEMM -> fragment-order A' ----------------
#define WST 72
__global__ __launch_bounds__(512) void k_tgt_readout_mfma(
    const float* __restrict__ om, const int* __restrict__ tgt_mask,
    unsigned short* __restrict__ Afrag) {
  const int b = blockIdx.x, dq = blockIdx.y, th = blockIdx.z;
  const int d0 = dq * 128, t0 = th * 128;
  __shared__ unsigned short Wb[128 * WST];
  __shared__ unsigned short omT[128 * WST];
  __shared__ float cntp[128 * 4];
  __shared__ float cnt_inv[128];
  const int tid = threadIdx.x;
  const int lane = tid & 63, w = tid >> 6;
  const int* mbase = tgt_mask + (size_t)b * 65536 + (size_t)t0 * 256;

  {
    const int t = tid >> 2, q = tid & 3;
    const int* mp = mbase + t * 256 + q * 64;
    int c = 0;
#pragma unroll
    for (int k = 0; k < 16; ++k) {
      int4 v = *(const int4*)(mp + 4 * k);
      c += v.x + v.y + v.z + v.w;
    }
    cntp[t * 4 + q] = (float)c;
  }
  __syncthreads();
  if (tid < 128) {
    float c = cntp[tid * 4] + cntp[tid * 4 + 1] + cntp[tid * 4 + 2] + cntp[tid * 4 + 3];
    cnt_inv[tid] = 1.0f / fmaxf(c, EPSF);
  }

  f32x4 acc[8];
#pragma unroll
  for (int di = 0; di < 8; ++di) acc[di] = (f32x4){0.f, 0.f, 0.f, 0.f};

  for (int uc = 0; uc < 4; ++uc) {
    const int ub = uc * 64;
    __syncthreads();
    {
      const int t = tid >> 2, ul0 = (tid & 3) * 16;
      const int* mp = mbase + t * 256 + ub + ul0;
      unsigned short* wp = Wb + t * WST + ul0;
#pragma unroll
      for (int k = 0; k < 4; ++k) {
        int4 v = *(const int4*)(mp + 4 * k);
        ushort4 h;
        h.x = v.x ? 0x3F80 : 0;
        h.y = v.y ? 0x3F80 : 0;
        h.z = v.z ? 0x3F80 : 0;
        h.w = v.w ? 0x3F80 : 0;
        *(ushort4*)(wp + 4 * k) = h;
      }
    }
    {
#pragma unroll
      for (int k = 0; k < 4; ++k) {
        const int idx = tid + 512 * k;
        const int u = idx >> 5, dl = (idx & 31) * 4;
        float4 v = *(const float4*)(om + (size_t)b * 131072 + (size_t)(ub + u) * 512 + d0 + dl);
        omT[(dl + 0) * WST + u] = bf16_rne(v.x);
        omT[(dl + 1) * WST + u] = bf16_rne(v.y);
        omT[(dl + 2) * WST + u] = bf16_rne(v.z);
        omT[(dl + 3) * WST + u] = bf16_rne(v.w);
      }
    }
    __syncthreads();
#pragma unroll
    for (int kt2 = 0; kt2 < 2; ++kt2) {
      const int ko = kt2 * 32 + (lane >> 4) * 8;
      bf16x8 wf = *(const bf16x8*)(Wb + (w * 16 + (lane & 15)) * WST + ko);
      bf16x8 of[8];
#pragma unroll
      for (int di = 0; di < 8; ++di)
        of[di] = *(const bf16x8*)(omT + (di * 16 + (lane & 15)) * WST + ko);
#pragma unroll
      for (int di = 0; di < 8; ++di)
        acc[di] = __builtin_amdgcn_mfma_f32_16x16x32_bf16(of[di], wf, acc[di], 0, 0, 0);
    }
  }

  const int tl = w * 16 + (lane & 15);
  const int rT = b * 256 + t0 + tl;
  const float inv = cnt_inv[tl];
#pragma unroll
  for (int di = 0; di < 8; ++di) {
    const int d = d0 + di * 16 + (lane >> 4) * 4;
    ushort4 o;
    o.x = bf16_rne(acc[di][0] * inv);
    o.y = bf16_rne(acc[di][1] * inv);
    o.z = bf16_rne(acc[di][2] * inv);
    o.w = bf16_rne(acc[di][3] * inv);
    const size_t off =
        (((size_t)(rT >> 4) * 16 + (d >> 5)) * 64 + ((d >> 3) & 3) * 16 + (rT & 15)) * 8 + (d & 7);
    *(ushort4*)(Afrag + off) = o;
  }
}

// ---------------- stage 2b: row squared norms from fragment-order A' ----------------
__global__ __launch_bounds__(256) void k_rowsq_frag(const unsigned short* __restrict__ Afrag,
                                                    float* __restrict__ sq) {
  const int r = blockIdx.x;
  const int tid = threadIdx.x;
  const int g = r >> 4, rl = r & 15;
  const int d = 2 * tid;
  const size_t off = ((size_t)((g * 16 + (d >> 5)) * 64 + ((d >> 3) & 3) * 16 + rl)) * 8 + (d & 7);
  ushort2 v = *(const ushort2*)(Afrag + off);
  float fx = bf16_to_f32(v.x), fy = bf16_to_f32(v.y);
  float s = fx * fx + fy * fy;
  s = block_reduce_sum_256(s);
  if (tid == 0) sq[r] = s;
}

// ---------------- stage 3: cross GEMM — B-stationary (128 cols), A streamed, 1 barrier ----------------
// Identical to round 7 except the sim writes are NON-TEMPORAL (no L2/L3 allocate),
// so the 134 MB write stream stops evicting the XCD-local A-panels.
__global__ __launch_bounds__(512, 2) void k_cross_mfma(
    const unsigned short* __restrict__ Afrag, const unsigned short* __restrict__ B,
    const float* __restrict__ tsq, const float* __restrict__ ssq,
    float* __restrict__ out) {
  __shared__ unsigned short Bs[128 * 512];
  const int tid = threadIdx.x;
  const int lane = tid & 63, w = tid >> 6;
  const int bid = blockIdx.x;
  const int xcd = bid & 7, idx = bid >> 3;
  const int row0 = (xcd * 2 + (idx >> 5)) * 512;
  const int col0 = (idx & 31) * 128;
  const int lr = lane & 15, lkh = lane >> 4;

#pragma unroll
  for (int t = 0; t < 16; ++t) {
    const int c = w * 16 + t;
    const int j = c >> 4, kt = c & 15;
    gload_lds16(B + (size_t)(col0 + j * 16 + lr) * 512 + kt * 32 + lkh * 8,
                Bs + (size_t)c * 512);
  }

  f32x4 acc[4][8];
#pragma unroll
  for (int i = 0; i < 4; ++i)
#pragma unroll
    for (int j = 0; j < 8; ++j) acc[i][j] = (f32x4){0.f, 0.f, 0.f, 0.f};

  __syncthreads();

  const unsigned short* ap = Afrag + ((size_t)(row0 >> 4) + w * 4) * (16 * 64 * 8);
#pragma unroll
  for (int kt = 0; kt < 16; ++kt) {
    bf16x8 af[4], bfr[8];
#pragma unroll
    for (int i = 0; i < 4; ++i)
      af[i] = *(const bf16x8*)(ap + (((size_t)i * 16 + kt) * 64 + lane) * 8);
#pragma unroll
    for (int j = 0; j < 8; ++j)
      bfr[j] = *(const bf16x8*)(Bs + ((j * 16 + kt) * 64 + lane) * 8);
#pragma unroll
    for (int i = 0; i < 4; ++i)
#pragma unroll
      for (int j = 0; j < 8; ++j)
        acc[i][j] = __builtin_amdgcn_mfma_f32_16x16x32_bf16(af[i], bfr[j], acc[i][j], 0, 0, 0);
  }

  const int cbase = col0 + (lane & 15);
  const int rbase = row0 + w * 64 + (lane >> 4) * 4;
  float ss[8];
#pragma unroll
  for (int j = 0; j < 8; ++j) ss[j] = ssq[cbase + j * 16];
#pragma unroll
  for (int i = 0; i < 4; ++i) {
#pragma unroll
    for (int r = 0; r < 4; ++r) {
      const int row = rbase + i * 16 + r;
      const float t2 = tsq[row];
      float* op = out + (size_t)row * 4096 + cbase;
#pragma unroll
      for (int j = 0; j < 8; ++j) {
        float d2 = t2 + ss[j] - 2.0f * acc[i][j][r];
        __builtin_nontemporal_store(expf(-sqrtf(fmaxf(d2, EPSF))), op + j * 16);
      }
    }
  }
}

// ---------------- stage 4: row L1 normalize (in-place f32, nt out-writes) ----------------
__global__ __launch_bounds__(256) void k_norm(float* __restrict__ out) {
  const size_t base = (size_t)blockIdx.x * 4096;
  const int tid = threadIdx.x;
  float4 v[4];
  float s = 0.f;
#pragma unroll
  for (int i = 0; i < 4; ++i) {
    v[i] = *(const float4*)(out + base + (size_t)(tid * 4 + i * 1024));
    s += v[i].x + v[i].y + v[i].z + v[i].w;
  }
  s = block_reduce_sum_256(s);
  const float inv = 1.0f / fmaxf(s, EPSF);
#pragma unroll
  for (int i = 0; i < 4; ++i) {
    f32x4 r;
    r[0] = v[i].x * inv;
    r[1] = v[i].y * inv;
    r[2] = v[i].z * inv;
    r[3] = v[i].w * inv;
    __builtin_nontemporal_store(r, (f32x4*)(out + base + (size_t)(tid * 4 + i * 1024)));
  }
}

extern "C" void kernel_launch(void* const* d_in, const int* in_sizes, int n_in,
                              void* d_out, int out_size, void* d_ws, size_t ws_size,
                              hipStream_t stream) {
  const float* m = (const float*)d_in[0];        // [4096,32,512]
  const float* om = (const float*)d_in[1];       // [32,256,512]
  const int* src_mask = (const int*)d_in[2];     // [4096,1,32]
  const int* tgt_mask = (const int*)d_in[3];     // [32,256,256]
  float* out = (float*)d_out;                    // [32,256,4096]

  float* ws = (float*)d_ws;
  float* ssq = ws;                                         // 4096 f32
  float* tsq = ssq + 4096;                                 // 8192 f32
  unsigned short* srcRb = (unsigned short*)(tsq + 8192);   // 4096*512 bf16 row-major
  unsigned short* Afrag = srcRb + 4096 * 512;              // 8192*512 bf16 fragment-order

  k_src_readout<<<2048, 256, 0, stream>>>(m, src_mask, srcRb, ssq);
  k_tgt_readout_mfma<<<dim3(32, 4, 2), 512, 0, stream>>>(om, tgt_mask, Afrag);
  k_rowsq_frag<<<8192, 256, 0, stream>>>(Afrag, tsq);
  k_cross_mfma<<<512, 512, 0, stream>>>(Afrag, srcRb, tsq, ssq, out);
  k_norm<<<8192, 256, 0, stream>>>(out);
}